// Round 2
// baseline (466163.281 us; speedup 1.0000x reference)
//
#include <hip/hip_runtime.h>
#include <cstddef>

namespace {
constexpr int NSTEP = 65536;
constexpr int D = 64;
constexpr int LDP = 68;          // padded LDS row stride (floats): (68r+c)%32 spreads column accesses
constexpr float JITTER = 1e-6f;
}

// One workgroup, 256 threads (4 waves). Thread (r = tid>>2, cq = tid&3) owns
// output elements [r][cq*16 .. cq*16+16) of every 64x64 matrix op.
__global__ __launch_bounds__(256) void kalman_seq_f32(
    const float* __restrict__ emis,   // [N]
    const float* __restrict__ Ht,     // [N,D]
    const float* __restrict__ F,      // [D,D]
    const float* __restrict__ Q,      // [D,D]
    const float* __restrict__ R,      // [1]
    const float* __restrict__ mu0,    // [D]
    const float* __restrict__ Sigma0, // [D,D]
    float* __restrict__ out)          // [N,D]
{
  __shared__ __align__(16) float Pl[D * LDP];   // covariance P
  __shared__ __align__(16) float Gl[D * LDP];   // G = F @ P_c
  __shared__ __align__(16) float FTl[D * LDP];  // FTl[k*LDP+c] = F[c][k]  (F transposed)
  __shared__ __align__(16) float hb[2][D];      // double-buffered H row
  __shared__ float vv[D];                       // v = P h
  __shared__ float Kv[D];                       // Kalman gain
  __shared__ float muc[D];                      // corrected mean (output)
  __shared__ float muv[D];                      // predicted mean (carry)
  __shared__ float red[2];                      // [0]=S, [1]=h.mu

  const int tid = threadIdx.x;
  const int r  = tid >> 2;         // 0..63 (4 consecutive lanes share a row -> same wave)
  const int c0 = (tid & 3) * 16;   // column chunk start

  // ---- init: stage Sigma0 -> P, F^T -> LDS; mu0; Q chunk into registers ----
  for (int i = tid; i < D * D; i += 256) {
    const int rr = i >> 6, cc = i & 63;
    Pl[rr * LDP + cc] = Sigma0[i];
    FTl[cc * LDP + rr] = F[i];     // FTl[k][c] = F[c][k]
  }
  if (tid < D) {
    muv[tid] = mu0[tid];
    hb[0][tid] = Ht[tid];
  }
  float Qreg[16];
  #pragma unroll
  for (int j = 0; j < 4; ++j) {
    const float4 q = *reinterpret_cast<const float4*>(&Q[r * D + c0 + 4 * j]);
    Qreg[4*j+0] = q.x; Qreg[4*j+1] = q.y; Qreg[4*j+2] = q.z; Qreg[4*j+3] = q.w;
  }
  const float rprime = R[0] + JITTER;   // S = (R + jitter) + h^T P h
  __syncthreads();

  for (int t = 0; t < NSTEP; ++t) {
    const float* __restrict__ h = hb[t & 1];
    // prefetch next step's observation row (lands ~4000 cy later)
    float hn = 0.f;
    if (tid < D && t + 1 < NSTEP) hn = Ht[(size_t)(t + 1) * D + tid];
    const float y = emis[t];

    // ---- v = P h : 4 partial lanes per row, shfl-combine ----
    float pv = 0.f;
    #pragma unroll
    for (int j = 0; j < 4; ++j) {
      const float4 p = *reinterpret_cast<const float4*>(&Pl[r * LDP + c0 + 4 * j]);
      pv += p.x * h[c0+4*j+0] + p.y * h[c0+4*j+1]
          + p.z * h[c0+4*j+2] + p.w * h[c0+4*j+3];
    }
    pv += __shfl_xor(pv, 1);
    pv += __shfl_xor(pv, 2);
    if ((tid & 3) == 0) vv[r] = pv;
    __syncthreads();

    // ---- S = r' + h.v (wave0) ; h.mu (wave1), concurrently ----
    if (tid < 64) {
      float val = h[tid] * vv[tid];
      #pragma unroll
      for (int o = 32; o > 0; o >>= 1) val += __shfl_xor(val, o);
      if (tid == 0) red[0] = rprime + val;
    } else if (tid < 128) {
      const int i2 = tid - 64;
      float val = h[i2] * muv[i2];
      #pragma unroll
      for (int o = 32; o > 0; o >>= 1) val += __shfl_xor(val, o);
      if (i2 == 0) red[1] = val;
    }
    __syncthreads();

    // ---- gain, corrected mean, output ----
    const float S = red[0];
    const float innov = y - red[1];
    if (tid < 64) {
      const float k = vv[tid] / S;
      Kv[tid] = k;
      const float mc = muv[tid] + k * innov;
      muc[tid] = mc;
      out[(size_t)t * D + tid] = mc;
    }
    __syncthreads();

    // ---- P_c = P - K v^T  (K S K^T == v v^T / S) ; mu' = F @ muc ----
    {
      const float kr = Kv[r];
      #pragma unroll
      for (int j = 0; j < 4; ++j) {
        float4 p = *reinterpret_cast<float4*>(&Pl[r * LDP + c0 + 4 * j]);
        p.x -= kr * vv[c0+4*j+0];
        p.y -= kr * vv[c0+4*j+1];
        p.z -= kr * vv[c0+4*j+2];
        p.w -= kr * vv[c0+4*j+3];
        *reinterpret_cast<float4*>(&Pl[r * LDP + c0 + 4 * j]) = p;
      }
      float pm = 0.f;
      #pragma unroll
      for (int c = 0; c < 16; ++c) pm += FTl[(c0 + c) * LDP + r] * muc[c0 + c];
      pm += __shfl_xor(pm, 1);
      pm += __shfl_xor(pm, 2);
      if ((tid & 3) == 0) muv[r] = pm;   // mu already fully consumed this step
    }
    __syncthreads();

    // ---- G = F @ P_c ----
    float acc[16];
    #pragma unroll
    for (int j = 0; j < 16; ++j) acc[j] = 0.f;
    #pragma unroll 4
    for (int kk = 0; kk < D; ++kk) {
      const float f = FTl[kk * LDP + r];   // == F[r][kk], broadcast x4 lanes
      #pragma unroll
      for (int j = 0; j < 4; ++j) {
        const float4 p = *reinterpret_cast<const float4*>(&Pl[kk * LDP + c0 + 4 * j]);
        acc[4*j+0] += f * p.x;
        acc[4*j+1] += f * p.y;
        acc[4*j+2] += f * p.z;
        acc[4*j+3] += f * p.w;
      }
    }
    #pragma unroll
    for (int j = 0; j < 4; ++j) {
      *reinterpret_cast<float4*>(&Gl[r * LDP + c0 + 4 * j]) =
          make_float4(acc[4*j+0], acc[4*j+1], acc[4*j+2], acc[4*j+3]);
    }
    __syncthreads();

    // ---- P' = G @ F^T + Q ----
    #pragma unroll
    for (int j = 0; j < 16; ++j) acc[j] = Qreg[j];
    #pragma unroll 4
    for (int kk = 0; kk < D; ++kk) {
      const float g = Gl[r * LDP + kk];
      #pragma unroll
      for (int j = 0; j < 4; ++j) {
        const float4 ft = *reinterpret_cast<const float4*>(&FTl[kk * LDP + c0 + 4 * j]);
        acc[4*j+0] += g * ft.x;
        acc[4*j+1] += g * ft.y;
        acc[4*j+2] += g * ft.z;
        acc[4*j+3] += g * ft.w;
      }
    }
    #pragma unroll
    for (int j = 0; j < 4; ++j) {
      *reinterpret_cast<float4*>(&Pl[r * LDP + c0 + 4 * j]) =
          make_float4(acc[4*j+0], acc[4*j+1], acc[4*j+2], acc[4*j+3]);
    }
    if (tid < D && t + 1 < NSTEP) hb[(t + 1) & 1][tid] = hn;
    __syncthreads();
  }
}

extern "C" void kernel_launch(void* const* d_in, const int* in_sizes, int n_in,
                              void* d_out, int out_size, void* d_ws, size_t ws_size,
                              hipStream_t stream) {
  (void)in_sizes; (void)n_in; (void)d_ws; (void)ws_size; (void)out_size;
  const float* emis   = (const float*)d_in[0];
  const float* Ht     = (const float*)d_in[1];
  const float* F      = (const float*)d_in[2];
  const float* Q      = (const float*)d_in[3];
  const float* R      = (const float*)d_in[4];
  const float* mu0    = (const float*)d_in[5];
  const float* Sigma0 = (const float*)d_in[6];
  float* out = (float*)d_out;
  hipLaunchKernelGGL(kalman_seq_f32, dim3(1), dim3(256), 0, stream,
                     emis, Ht, F, Q, R, mu0, Sigma0, out);
}

// Round 3
// 152296.558 us; speedup vs baseline: 3.0609x; 3.0609x over previous
//
#include <hip/hip_runtime.h>
#include <cstddef>

typedef float f32x4 __attribute__((ext_vector_type(4)));
typedef short bf16x8 __attribute__((ext_vector_type(8)));
typedef unsigned short u16x4 __attribute__((ext_vector_type(4)));

namespace {
constexpr int NSTEP = 65536;
constexpr int D = 64;
constexpr int SB = 72;   // bf16 LDS row stride in shorts (144 B: 16B-aligned, conflict-light)
constexpr int SF = 68;   // f32 LDS row stride in floats (272 B)
constexpr float JITTER = 1e-6f;
}

__device__ __forceinline__ float bf2f(unsigned short h) {
  union { unsigned u; float f; } v; v.u = ((unsigned)h) << 16; return v.f;
}
__device__ __forceinline__ unsigned short f2bf(float x) {
  union { float f; unsigned u; } v; v.f = x;
  unsigned r = (v.u + 0x7FFFu + ((v.u >> 16) & 1u)) >> 16;
  return (unsigned short)r;
}
// split 8 f32 (two f32x4) into hi/lo bf16x8 fragments
__device__ __forceinline__ void split8(const f32x4& a, const f32x4& b, bf16x8& hi, bf16x8& lo) {
  float x[8] = {a[0],a[1],a[2],a[3],b[0],b[1],b[2],b[3]};
  #pragma unroll
  for (int j = 0; j < 8; ++j) {
    unsigned short h = f2bf(x[j]);
    hi[j] = (short)h;
    lo[j] = (short)f2bf(x[j] - bf2f(h));
  }
}

// One workgroup, 256 threads = 4 waves (2x2 quadrants of the 64x64 matrices).
// Per step:  M1 = P @ F^T (MFMA, bf16 hi/lo x3)    [phase 0, + v = P h partials]
//            w = F v, mu' = F(mu + (innov/S) v)     [phase 1 VALU matvec, + M1T store]
//            P' = F @ M1 + Q - w w^T / S            [phase 2 MFMA, epilogue-folded]
// P and P' stored transposed (== themselves, symmetric) so all MFMA fragment
// reads are contiguous b128 row reads and all D-fragment stores are b64s.
__global__ __launch_bounds__(256, 1) void kalman_mfma(
    const float* __restrict__ emis,   // [N]
    const float* __restrict__ Ht,     // [N,D]
    const float* __restrict__ Fg,     // [D,D]
    const float* __restrict__ Qg,     // [D,D]
    const float* __restrict__ Rg,     // [1]
    const float* __restrict__ mu0,    // [D]
    const float* __restrict__ Sigma0, // [D,D]
    float* __restrict__ out)          // [N,D]
{
  __shared__ __align__(16) unsigned short PLhi[D * SB], PLlo[D * SB];   // P (sym, "transposed")
  __shared__ __align__(16) unsigned short M1Thi[D * SB], M1Tlo[D * SB]; // M1^T = (P F^T)^T
  __shared__ __align__(16) float FL[D * SF];        // F row-major f32 (matvecs)
  __shared__ __align__(16) float hb_l[2][D];        // double-buffered H row
  __shared__ __align__(16) float mu_l[2][D];        // double-buffered predicted mean
  __shared__ __align__(16) float vv_l[D];           // v = P h
  __shared__ __align__(16) float w_l[D];            // w = F v
  __shared__ __align__(16) float sred_l[4];         // per-wave partials of h.v
  __shared__ float red_hmu;                         // h . mu

  const int tid = threadIdx.x;
  const int l  = tid & 63;         // lane
  const int lg = l >> 4;           // lane group 0..3 (k-octet)
  const int lm = l & 15;           // m/n index within 16-tile
  const int wv = tid >> 6;         // wave 0..3
  const int R0 = (wv >> 1) * 32;   // quadrant row base
  const int C0 = (wv & 1) * 32;    // quadrant col base
  const int r  = tid >> 2;         // matvec row 0..63
  const int q  = tid & 3;          // matvec column-quarter
  const int c0 = q * 16;           // matvec column base

  // ---------------- init ----------------
  for (int i = tid; i < D * D; i += 256) {
    const int rr = i >> 6, cc = i & 63;
    const float s = Sigma0[i];
    const unsigned short h = f2bf(s);
    PLhi[rr * SB + cc] = h;
    PLlo[rr * SB + cc] = f2bf(s - bf2f(h));
    FL[rr * SF + cc] = Fg[i];
  }
  if (tid < D) { mu_l[0][tid] = mu0[tid]; hb_l[0][tid] = Ht[tid]; }

  // F fragments in registers, packed with kappa(g,j) = 8g+j (consistent for A and B):
  //  FB (matmul1 B = F^T):  FB[nt][kt] lane holds F[C0+16nt+lm][8lg+j+32kt]
  //  FA (matmul2 A = F):    FA[mt][kt] lane holds F[R0+16mt+lm][8lg+j+32kt]
  bf16x8 FBhi[2][2], FBlo[2][2], FAhi[2][2], FAlo[2][2];
  #pragma unroll
  for (int nt = 0; nt < 2; ++nt)
    #pragma unroll
    for (int kt = 0; kt < 2; ++kt) {
      {
        const int row = C0 + 16 * nt + lm;
        const int base = row * 64 + 8 * lg + 32 * kt;
        split8(*(const f32x4*)&Fg[base], *(const f32x4*)&Fg[base + 4], FBhi[nt][kt], FBlo[nt][kt]);
      }
      {
        const int row = R0 + 16 * nt + lm;   // nt plays mt here
        const int base = row * 64 + 8 * lg + 32 * kt;
        split8(*(const f32x4*)&Fg[base], *(const f32x4*)&Fg[base + 4], FAhi[nt][kt], FAlo[nt][kt]);
      }
    }

  // Q at D-fragment positions: Qc[mt][nt][j] = Q[R0+16mt+4lg+j][C0+16nt+lm]
  f32x4 Qc[2][2];
  #pragma unroll
  for (int mt = 0; mt < 2; ++mt)
    #pragma unroll
    for (int nt = 0; nt < 2; ++nt)
      #pragma unroll
      for (int j = 0; j < 4; ++j)
        Qc[mt][nt][j] = Qg[(R0 + 16 * mt + 4 * lg + j) * 64 + (C0 + 16 * nt + lm)];

  const float rp = Rg[0] + JITTER;
  __syncthreads();

  #pragma unroll 1
  for (int t = 0; t < NSTEP; ++t) {
    const int p = t & 1;
    const float y = emis[t];
    float hnext = 0.f;
    if (tid < D && t + 1 < NSTEP) hnext = Ht[(size_t)(t + 1) * D + tid];

    // ================= PHASE 0: M1 = P @ F^T  (+ v = P h partials) =================
    // v partials: thread (r,q) dots P[r][c0..c0+16) with h
    float ha[16];
    #pragma unroll
    for (int i2 = 0; i2 < 4; ++i2) {
      const f32x4 h4 = *(const f32x4*)&hb_l[p][c0 + 4 * i2];
      #pragma unroll
      for (int j = 0; j < 4; ++j) ha[4 * i2 + j] = h4[j];
    }
    float pv = 0.f;
    #pragma unroll
    for (int half = 0; half < 2; ++half) {
      const bf16x8 phi = *(const bf16x8*)&PLhi[r * SB + c0 + 8 * half];
      const bf16x8 plo = *(const bf16x8*)&PLlo[r * SB + c0 + 8 * half];
      #pragma unroll
      for (int j = 0; j < 8; ++j)
        pv += (bf2f((unsigned short)phi[j]) + bf2f((unsigned short)plo[j])) * ha[8 * half + j];
    }
    const float hr = hb_l[p][r];

    // wave0: h . mu reduce
    if (tid < 64) {
      float hm = hb_l[p][tid] * mu_l[p][tid];
      #pragma unroll
      for (int o = 32; o > 0; o >>= 1) hm += __shfl_xor(hm, o);
      if (tid == 0) red_hmu = hm;
    }

    // A fragments of matmul1 (A = P): lane holds P[R0+16mt+lm][8lg+j+32kt]
    bf16x8 Ahi[2][2], Alo[2][2];
    #pragma unroll
    for (int mt = 0; mt < 2; ++mt)
      #pragma unroll
      for (int kt = 0; kt < 2; ++kt) {
        const int off = (R0 + 16 * mt + lm) * SB + 8 * lg + 32 * kt;
        Ahi[mt][kt] = *(const bf16x8*)&PLhi[off];
        Alo[mt][kt] = *(const bf16x8*)&PLlo[off];
      }

    f32x4 acc1[2][2];
    #pragma unroll
    for (int mt = 0; mt < 2; ++mt)
      #pragma unroll
      for (int nt = 0; nt < 2; ++nt)
        acc1[mt][nt] = (f32x4){0.f, 0.f, 0.f, 0.f};
    #pragma unroll
    for (int kt = 0; kt < 2; ++kt)
      #pragma unroll
      for (int mt = 0; mt < 2; ++mt)
        #pragma unroll
        for (int nt = 0; nt < 2; ++nt) {
          acc1[mt][nt] = __builtin_amdgcn_mfma_f32_16x16x32_bf16(Ahi[mt][kt], FBhi[nt][kt], acc1[mt][nt], 0, 0, 0);
          acc1[mt][nt] = __builtin_amdgcn_mfma_f32_16x16x32_bf16(Ahi[mt][kt], FBlo[nt][kt], acc1[mt][nt], 0, 0, 0);
          acc1[mt][nt] = __builtin_amdgcn_mfma_f32_16x16x32_bf16(Alo[mt][kt], FBhi[nt][kt], acc1[mt][nt], 0, 0, 0);
        }

    // finish v partial: combine 4-lane groups, publish vv; per-wave h.v partial
    {
      float pvs = pv;
      pvs += __shfl_xor(pvs, 1);
      pvs += __shfl_xor(pvs, 2);
      if (q == 0) vv_l[r] = pvs;
      float sp = hr * pv;   // partial-product form: sum over all lanes == h^T v (wave rows)
      #pragma unroll
      for (int o = 32; o > 0; o >>= 1) sp += __shfl_xor(sp, o);
      if (l == 0) sred_l[wv] = sp;
    }
    __syncthreads();   // B1: vv, sred, red_hmu ready

    // ================= PHASE 1: scalars + matvecs + M1T store =================
    const f32x4 sr4 = *(const f32x4*)&sred_l[0];
    const float S = rp + sr4[0] + sr4[1] + sr4[2] + sr4[3];
    const float invS = 1.0f / S;
    const float innov = y - red_hmu;
    const float kg = innov * invS;

    // dual matvec sharing F reads: w = F v ; mu' = F (mu + kg v)
    float accw = 0.f, accm = 0.f;
    #pragma unroll
    for (int i2 = 0; i2 < 4; ++i2) {
      const f32x4 fl  = *(const f32x4*)&FL[r * SF + c0 + 4 * i2];
      const f32x4 vvv = *(const f32x4*)&vv_l[c0 + 4 * i2];
      const f32x4 muv = *(const f32x4*)&mu_l[p][c0 + 4 * i2];
      #pragma unroll
      for (int j = 0; j < 4; ++j) {
        accw += fl[j] * vvv[j];
        accm += fl[j] * (muv[j] + kg * vvv[j]);
      }
    }
    accw += __shfl_xor(accw, 1); accw += __shfl_xor(accw, 2);
    accm += __shfl_xor(accm, 1); accm += __shfl_xor(accm, 2);
    if (q == 0) w_l[r] = accw;
    // (accm == mu'[r] held in register until phase 2)

    // store M1^T: D-frag (row 4lg+reg, col lm) -> M1T[col][row..row+4) as b64 hi/lo
    #pragma unroll
    for (int mt = 0; mt < 2; ++mt)
      #pragma unroll
      for (int nt = 0; nt < 2; ++nt) {
        const int c  = C0 + 16 * nt + lm;
        const int rb = R0 + 16 * mt + 4 * lg;
        const f32x4 dv = acc1[mt][nt];
        u16x4 h4, l4;
        #pragma unroll
        for (int j = 0; j < 4; ++j) {
          const unsigned short hh = f2bf(dv[j]);
          h4[j] = hh;
          l4[j] = f2bf(dv[j] - bf2f(hh));
        }
        *(u16x4*)&M1Thi[c * SB + rb] = h4;
        *(u16x4*)&M1Tlo[c * SB + rb] = l4;
      }
    __syncthreads();   // B2: M1T, w ready

    // ================= PHASE 2: P' = F @ M1 + Q - w w^T/S =================
    f32x4 acc2[2][2];
    #pragma unroll
    for (int mt = 0; mt < 2; ++mt) {
      const f32x4 wr = *(const f32x4*)&w_l[R0 + 16 * mt + 4 * lg];
      #pragma unroll
      for (int nt = 0; nt < 2; ++nt) {
        const float wc = w_l[C0 + 16 * nt + lm] * invS;
        #pragma unroll
        for (int j = 0; j < 4; ++j)
          acc2[mt][nt][j] = Qc[mt][nt][j] - wr[j] * wc;
      }
    }
    #pragma unroll
    for (int kt = 0; kt < 2; ++kt) {
      bf16x8 Bhi[2], Blo[2];
      #pragma unroll
      for (int nt = 0; nt < 2; ++nt) {
        const int off = (C0 + 16 * nt + lm) * SB + 8 * lg + 32 * kt;
        Bhi[nt] = *(const bf16x8*)&M1Thi[off];
        Blo[nt] = *(const bf16x8*)&M1Tlo[off];
      }
      #pragma unroll
      for (int mt = 0; mt < 2; ++mt)
        #pragma unroll
        for (int nt = 0; nt < 2; ++nt) {
          acc2[mt][nt] = __builtin_amdgcn_mfma_f32_16x16x32_bf16(FAhi[mt][kt], Bhi[nt], acc2[mt][nt], 0, 0, 0);
          acc2[mt][nt] = __builtin_amdgcn_mfma_f32_16x16x32_bf16(FAhi[mt][kt], Blo[nt], acc2[mt][nt], 0, 0, 0);
          acc2[mt][nt] = __builtin_amdgcn_mfma_f32_16x16x32_bf16(FAlo[mt][kt], Bhi[nt], acc2[mt][nt], 0, 0, 0);
        }
    }

    // store P' transposed (== P', symmetric) as next step's P
    #pragma unroll
    for (int mt = 0; mt < 2; ++mt)
      #pragma unroll
      for (int nt = 0; nt < 2; ++nt) {
        const int c  = C0 + 16 * nt + lm;
        const int rb = R0 + 16 * mt + 4 * lg;
        const f32x4 dv = acc2[mt][nt];
        u16x4 h4, l4;
        #pragma unroll
        for (int j = 0; j < 4; ++j) {
          const unsigned short hh = f2bf(dv[j]);
          h4[j] = hh;
          l4[j] = f2bf(dv[j] - bf2f(hh));
        }
        *(u16x4*)&PLhi[c * SB + rb] = h4;
        *(u16x4*)&PLlo[c * SB + rb] = l4;
      }

    // mean carry, output, h double-buffer
    if (q == 0) mu_l[p ^ 1][r] = accm;
    if (tid < D) {
      out[(size_t)t * D + tid] = mu_l[p][tid] + kg * vv_l[tid];  // mu_c
      if (t + 1 < NSTEP) hb_l[p ^ 1][tid] = hnext;
    }
    __syncthreads();   // B3: P', mu, h ready for next step
  }
}

extern "C" void kernel_launch(void* const* d_in, const int* in_sizes, int n_in,
                              void* d_out, int out_size, void* d_ws, size_t ws_size,
                              hipStream_t stream) {
  (void)in_sizes; (void)n_in; (void)d_ws; (void)ws_size; (void)out_size;
  const float* emis   = (const float*)d_in[0];
  const float* Ht     = (const float*)d_in[1];
  const float* F      = (const float*)d_in[2];
  const float* Q      = (const float*)d_in[3];
  const float* R      = (const float*)d_in[4];
  const float* mu0    = (const float*)d_in[5];
  const float* Sigma0 = (const float*)d_in[6];
  float* out = (float*)d_out;
  hipLaunchKernelGGL(kalman_mfma, dim3(1), dim3(256), 0, stream,
                     emis, Ht, F, Q, R, mu0, Sigma0, out);
}

// Round 5
// 123461.609 us; speedup vs baseline: 3.7758x; 1.2336x over previous
//
#include <hip/hip_runtime.h>
#include <cstddef>

typedef float f32x4 __attribute__((ext_vector_type(4)));
typedef short bf16x8 __attribute__((ext_vector_type(8)));

namespace {
constexpr int D = 64;
constexpr int SB = 72;   // bf16 LDS row stride (shorts)
constexpr int SF = 68;   // f32 LDS row stride (floats)
constexpr float JITTER = 1e-6f;
}

__device__ __forceinline__ unsigned fbits(float x){ union{float f;unsigned u;}v; v.f=x; return v.u; }
__device__ __forceinline__ float bitsf(unsigned u){ union{unsigned u;float f;}v; v.u=u; return v.f; }
__device__ __forceinline__ float bf2f(short h){ return bitsf(((unsigned)(unsigned short)h)<<16); }

// truncation-based hi/lo split of an f32x4 into two packed-bf16 uint2 (1 v_perm per pair)
__device__ __forceinline__ void split4(const f32x4 dv, uint2& hi, uint2& lo) {
  const unsigned b0 = fbits(dv[0]), b1 = fbits(dv[1]), b2 = fbits(dv[2]), b3 = fbits(dv[3]);
  hi.x = __builtin_amdgcn_perm(b1, b0, 0x07060302u);
  hi.y = __builtin_amdgcn_perm(b3, b2, 0x07060302u);
  const float r0 = dv[0] - bitsf(b0 & 0xFFFF0000u);
  const float r1 = dv[1] - bitsf(b1 & 0xFFFF0000u);
  const float r2 = dv[2] - bitsf(b2 & 0xFFFF0000u);
  const float r3 = dv[3] - bitsf(b3 & 0xFFFF0000u);
  lo.x = __builtin_amdgcn_perm(fbits(r1), fbits(r0), 0x07060302u);
  lo.y = __builtin_amdgcn_perm(fbits(r3), fbits(r2), 0x07060302u);
}

// init-only: split 8 consecutive f32 into hi/lo bf16x8
__device__ __forceinline__ void split8t(const float* src, bf16x8& hi, bf16x8& lo) {
  #pragma unroll
  for (int j = 0; j < 8; ++j) {
    const unsigned b = fbits(src[j]);
    hi[j] = (short)(b >> 16);
    const float r = src[j] - bitsf(b & 0xFFFF0000u);
    lo[j] = (short)(fbits(r) >> 16);
  }
}

// 8 waves: waves 0-3 = MFMA (2x2 quadrants of 64x64), waves 4-7 = scalar (16 rows each).
// Per step (3 barriers):
//  seg1: MFMA: M1 = P @ F^T (24 mfma) -> M1T(bf16 hi/lo)   || scalar: v=Ph partials, h.mu, S-partials, prefetch
//  seg2: MFMA: acc2 = Q + F @ M1 (24 mfma)                 || scalar: S,kg, w = M1^T h, out, mu_c, h-buf
//  seg3: MFMA: acc2 -= w w^T/S; store P'(bf16 hi/lo)       || scalar: mu' = F mu_c
__global__ __launch_bounds__(512, 1) void kalman_ws(
    const float* __restrict__ emis,   // [N]
    const float* __restrict__ Ht,     // [N,D]
    const float* __restrict__ Fg,     // [D,D]
    const float* __restrict__ Qg,     // [D,D]
    const float* __restrict__ Rg,     // [1]
    const float* __restrict__ mu0,    // [D]
    const float* __restrict__ Sigma0, // [D,D]
    float* __restrict__ out,          // [N,D]
    int n)
{
  __shared__ __align__(16) unsigned short PLhi[D * SB], PLlo[D * SB];   // P (sym, transposed store)
  __shared__ __align__(16) unsigned short M1Thi[D * SB], M1Tlo[D * SB]; // M1^T = F P
  __shared__ __align__(16) float FL[D * SF];    // F row-major f32
  __shared__ __align__(16) float hb_l[2][D];    // H row, double-buffered
  __shared__ __align__(16) float mu_l[2][D];    // predicted mean, double-buffered
  __shared__ __align__(16) float mu_c_l[D];     // corrected mean
  __shared__ __align__(16) float vv_l[D];       // v = P h
  __shared__ __align__(16) float w_l[D];        // w = F v
  __shared__ __align__(16) float sred_l[4];     // per-scalar-wave partials of h.v
  __shared__ __align__(16) float sred2_l[4];    // per-scalar-wave partials of h.mu

  const int tid = threadIdx.x;
  const int l   = tid & 63;        // lane
  const int lg  = l >> 4;          // lane group (k-octet)
  const int lm  = l & 15;          // m/n within 16-tile
  const int wv  = tid >> 6;        // wave 0..7
  const int sq  = wv & 3;          // quadrant / scalar-wave index
  const int R0  = (sq >> 1) * 32;  // quadrant row base
  const int C0  = (sq & 1) * 32;   // quadrant col base
  const int W0  = sq * 16;         // scalar wave row base
  const int srow = W0 + (l >> 2);  // scalar matvec row
  const int q   = l & 3;           // scalar column-quarter
  const int c0  = q * 16;

  // ---------------- init ----------------
  for (int i = tid; i < D * D; i += 512) {
    const int rr = i >> 6, cc = i & 63;
    const float s = Sigma0[i];
    const unsigned b = fbits(s);
    PLhi[rr * SB + cc] = (unsigned short)(b >> 16);
    PLlo[rr * SB + cc] = (unsigned short)(fbits(s - bitsf(b & 0xFFFF0000u)) >> 16);
    FL[rr * SF + cc] = Fg[i];
  }
  if (tid < D) { mu_l[0][tid] = mu0[tid]; hb_l[0][tid] = Ht[tid]; }

  // F fragments in registers, kappa(lg,j)=8lg+j consistent for A and B (validated in r3):
  bf16x8 FBhi[2][2], FBlo[2][2], FAhi[2][2], FAlo[2][2];
  #pragma unroll
  for (int nt = 0; nt < 2; ++nt)
    #pragma unroll
    for (int kt = 0; kt < 2; ++kt) {
      split8t(&Fg[(C0 + 16 * nt + lm) * 64 + 8 * lg + 32 * kt], FBhi[nt][kt], FBlo[nt][kt]);
      split8t(&Fg[(R0 + 16 * nt + lm) * 64 + 8 * lg + 32 * kt], FAhi[nt][kt], FAlo[nt][kt]);
    }
  f32x4 Qc[2][2];
  #pragma unroll
  for (int mt = 0; mt < 2; ++mt)
    #pragma unroll
    for (int nt = 0; nt < 2; ++nt)
      #pragma unroll
      for (int j = 0; j < 4; ++j)
        Qc[mt][nt][j] = Qg[(R0 + 16 * mt + 4 * lg + j) * 64 + (C0 + 16 * nt + lm)];

  const float rp = Rg[0] + JITTER;
  __syncthreads();

  f32x4 acc2[2][2];          // lives seg2 -> seg3 (MFMA waves)
  f32x4 hq0, hq1, hq2, hq3;  // scalar: h chunk, loaded seg1, reused seg2
  float y = 0.f, hn = 0.f;

  #pragma unroll 1
  for (int t = 0; t < n; ++t) {
    const int p = t & 1;

    // ======================= SEGMENT 1 =======================
    if (wv < 4) {
      // ---- M1 = P @ F^T ----
      bf16x8 Ahi[2][2], Alo[2][2];
      #pragma unroll
      for (int mt = 0; mt < 2; ++mt)
        #pragma unroll
        for (int kt = 0; kt < 2; ++kt) {
          const int off = (R0 + 16 * mt + lm) * SB + 8 * lg + 32 * kt;
          Ahi[mt][kt] = *(const bf16x8*)&PLhi[off];
          Alo[mt][kt] = *(const bf16x8*)&PLlo[off];
        }
      f32x4 acc1[2][2];
      #pragma unroll
      for (int mt = 0; mt < 2; ++mt)
        #pragma unroll
        for (int nt = 0; nt < 2; ++nt)
          acc1[mt][nt] = (f32x4){0.f, 0.f, 0.f, 0.f};
      #pragma unroll
      for (int kt = 0; kt < 2; ++kt)
        #pragma unroll
        for (int mt = 0; mt < 2; ++mt)
          #pragma unroll
          for (int nt = 0; nt < 2; ++nt) {
            acc1[mt][nt] = __builtin_amdgcn_mfma_f32_16x16x32_bf16(Ahi[mt][kt], FBhi[nt][kt], acc1[mt][nt], 0, 0, 0);
            acc1[mt][nt] = __builtin_amdgcn_mfma_f32_16x16x32_bf16(Ahi[mt][kt], FBlo[nt][kt], acc1[mt][nt], 0, 0, 0);
            acc1[mt][nt] = __builtin_amdgcn_mfma_f32_16x16x32_bf16(Alo[mt][kt], FBhi[nt][kt], acc1[mt][nt], 0, 0, 0);
          }
      // ---- convert + store M1^T ----
      #pragma unroll
      for (int mt = 0; mt < 2; ++mt)
        #pragma unroll
        for (int nt = 0; nt < 2; ++nt) {
          const int idx = (C0 + 16 * nt + lm) * SB + R0 + 16 * mt + 4 * lg;
          uint2 h2, l2;
          split4(acc1[mt][nt], h2, l2);
          *reinterpret_cast<uint2*>(&M1Thi[idx]) = h2;
          *reinterpret_cast<uint2*>(&M1Tlo[idx]) = l2;
        }
    } else {
      // ---- scalar: v = P h partials, reductions, prefetch ----
      y = emis[t];
      if (sq == 1 && t + 1 < n) hn = Ht[(size_t)(t + 1) * D + l];
      hq0 = *(const f32x4*)&hb_l[p][c0 + 0];
      hq1 = *(const f32x4*)&hb_l[p][c0 + 4];
      hq2 = *(const f32x4*)&hb_l[p][c0 + 8];
      hq3 = *(const f32x4*)&hb_l[p][c0 + 12];
      const bf16x8 ph0 = *(const bf16x8*)&PLhi[srow * SB + c0];
      const bf16x8 ph1 = *(const bf16x8*)&PLhi[srow * SB + c0 + 8];
      const bf16x8 pl0 = *(const bf16x8*)&PLlo[srow * SB + c0];
      const bf16x8 pl1 = *(const bf16x8*)&PLlo[srow * SB + c0 + 8];
      float pv = 0.f;
      #pragma unroll
      for (int j = 0; j < 4; ++j) {
        pv += (bf2f(ph0[j])     + bf2f(pl0[j]))     * hq0[j];
        pv += (bf2f(ph0[j + 4]) + bf2f(pl0[j + 4])) * hq1[j];
        pv += (bf2f(ph1[j])     + bf2f(pl1[j]))     * hq2[j];
        pv += (bf2f(ph1[j + 4]) + bf2f(pl1[j + 4])) * hq3[j];
      }
      const float hr = hb_l[p][srow];
      float pvs = pv;
      pvs += __shfl_xor(pvs, 1);
      pvs += __shfl_xor(pvs, 2);
      if (q == 0) vv_l[srow] = pvs;
      float sp = hr * pv;   // sum over lanes == partial h.v over rows W0..W0+15
      #pragma unroll
      for (int o = 32; o > 0; o >>= 1) sp += __shfl_xor(sp, o);
      if (l == 0) sred_l[sq] = sp;
      float hm = (l < 16) ? hb_l[p][W0 + (l & 15)] * mu_l[p][W0 + (l & 15)] : 0.f;
      #pragma unroll
      for (int o = 8; o > 0; o >>= 1) hm += __shfl_xor(hm, o);
      if (l == 0) sred2_l[sq] = hm;
    }
    __syncthreads();   // B_mid: M1T, vv, sred, sred2 visible

    // ======================= SEGMENT 2 =======================
    if (wv < 4) {
      // ---- acc2 = Q + F @ M1 ----
      #pragma unroll
      for (int mt = 0; mt < 2; ++mt)
        #pragma unroll
        for (int nt = 0; nt < 2; ++nt)
          acc2[mt][nt] = Qc[mt][nt];
      #pragma unroll
      for (int kt = 0; kt < 2; ++kt) {
        bf16x8 Bhi[2], Blo[2];
        #pragma unroll
        for (int nt = 0; nt < 2; ++nt) {
          const int off = (C0 + 16 * nt + lm) * SB + 8 * lg + 32 * kt;
          Bhi[nt] = *(const bf16x8*)&M1Thi[off];
          Blo[nt] = *(const bf16x8*)&M1Tlo[off];
        }
        #pragma unroll
        for (int mt = 0; mt < 2; ++mt)
          #pragma unroll
          for (int nt = 0; nt < 2; ++nt) {
            acc2[mt][nt] = __builtin_amdgcn_mfma_f32_16x16x32_bf16(FAhi[mt][kt], Bhi[nt], acc2[mt][nt], 0, 0, 0);
            acc2[mt][nt] = __builtin_amdgcn_mfma_f32_16x16x32_bf16(FAhi[mt][kt], Blo[nt], acc2[mt][nt], 0, 0, 0);
            acc2[mt][nt] = __builtin_amdgcn_mfma_f32_16x16x32_bf16(FAlo[mt][kt], Bhi[nt], acc2[mt][nt], 0, 0, 0);
          }
      }
    } else {
      // ---- scalar: S, gain, w = M1^T h, out, mu_c, h-buffer ----
      const float S = rp + sred_l[0] + sred_l[1] + sred_l[2] + sred_l[3];
      const float invS = 1.0f / S;
      const float hmu = sred2_l[0] + sred2_l[1] + sred2_l[2] + sred2_l[3];
      const float kg = (y - hmu) * invS;
      const bf16x8 mh0 = *(const bf16x8*)&M1Thi[srow * SB + c0];
      const bf16x8 mh1 = *(const bf16x8*)&M1Thi[srow * SB + c0 + 8];
      const bf16x8 ml0 = *(const bf16x8*)&M1Tlo[srow * SB + c0];
      const bf16x8 ml1 = *(const bf16x8*)&M1Tlo[srow * SB + c0 + 8];
      float pw = 0.f;
      #pragma unroll
      for (int j = 0; j < 4; ++j) {
        pw += (bf2f(mh0[j])     + bf2f(ml0[j]))     * hq0[j];
        pw += (bf2f(mh0[j + 4]) + bf2f(ml0[j + 4])) * hq1[j];
        pw += (bf2f(mh1[j])     + bf2f(ml1[j]))     * hq2[j];
        pw += (bf2f(mh1[j + 4]) + bf2f(ml1[j + 4])) * hq3[j];
      }
      pw += __shfl_xor(pw, 1);
      pw += __shfl_xor(pw, 2);
      if (q == 0) w_l[srow] = pw;
      if (sq == 0) out[(size_t)t * D + l] = mu_l[p][l] + kg * vv_l[l];
      if (sq == 2) mu_c_l[l] = mu_l[p][l] + kg * vv_l[l];
      if (sq == 1 && t + 1 < n) hb_l[p ^ 1][l] = hn;
    }
    __syncthreads();   // B_w: w, mu_c visible; matmul2 accs done

    // ======================= SEGMENT 3 =======================
    if (wv < 4) {
      const float S = rp + sred_l[0] + sred_l[1] + sred_l[2] + sred_l[3];
      const float invS = 1.0f / S;
      #pragma unroll
      for (int mt = 0; mt < 2; ++mt) {
        const f32x4 wr = *(const f32x4*)&w_l[R0 + 16 * mt + 4 * lg];
        #pragma unroll
        for (int nt = 0; nt < 2; ++nt) {
          const float wc = w_l[C0 + 16 * nt + lm] * invS;
          #pragma unroll
          for (int j = 0; j < 4; ++j)
            acc2[mt][nt][j] -= wr[j] * wc;
          const int idx = (C0 + 16 * nt + lm) * SB + R0 + 16 * mt + 4 * lg;
          uint2 h2, l2;
          split4(acc2[mt][nt], h2, l2);
          *reinterpret_cast<uint2*>(&PLhi[idx]) = h2;
          *reinterpret_cast<uint2*>(&PLlo[idx]) = l2;
        }
      }
    } else {
      // ---- scalar: mu' = F mu_c ----
      float pm = 0.f;
      #pragma unroll
      for (int i2 = 0; i2 < 4; ++i2) {
        const f32x4 fl = *(const f32x4*)&FL[srow * SF + c0 + 4 * i2];
        const f32x4 mc = *(const f32x4*)&mu_c_l[c0 + 4 * i2];
        #pragma unroll
        for (int j = 0; j < 4; ++j) pm += fl[j] * mc[j];
      }
      pm += __shfl_xor(pm, 1);
      pm += __shfl_xor(pm, 2);
      if (q == 0) mu_l[p ^ 1][srow] = pm;
    }
    __syncthreads();   // B_end: P', mu' ready for next step
  }
}

extern "C" void kernel_launch(void* const* d_in, const int* in_sizes, int n_in,
                              void* d_out, int out_size, void* d_ws, size_t ws_size,
                              hipStream_t stream) {
  (void)n_in; (void)d_ws; (void)ws_size; (void)out_size;
  const float* emis   = (const float*)d_in[0];
  const float* Ht     = (const float*)d_in[1];
  const float* F      = (const float*)d_in[2];
  const float* Q      = (const float*)d_in[3];
  const float* R      = (const float*)d_in[4];
  const float* mu0    = (const float*)d_in[5];
  const float* Sigma0 = (const float*)d_in[6];
  float* out = (float*)d_out;
  const int n = in_sizes[0];
  hipLaunchKernelGGL(kalman_ws, dim3(1), dim3(512), 0, stream,
                     emis, Ht, F, Q, R, mu0, Sigma0, out, n);
}

// Round 6
// 115510.815 us; speedup vs baseline: 4.0357x; 1.0688x over previous
//
#include <hip/hip_runtime.h>
#include <cstddef>

typedef float f32x4 __attribute__((ext_vector_type(4)));
typedef short bf16x8 __attribute__((ext_vector_type(8)));

namespace {
constexpr int D = 64;
constexpr int SB = 72;   // bf16 LDS row stride (shorts)
constexpr int SF = 68;   // f32 LDS row stride (floats)
constexpr float JITTER = 1e-6f;
}

__device__ __forceinline__ unsigned fbits(float x){ union{float f;unsigned u;}v; v.f=x; return v.u; }
__device__ __forceinline__ float bitsf(unsigned u){ union{unsigned u;float f;}v; v.u=u; return v.f; }
__device__ __forceinline__ float bf2f(short h){ return bitsf(((unsigned)(unsigned short)h)<<16); }

// truncation-based hi/lo split of an f32x4 into two packed-bf16 uint2
__device__ __forceinline__ void split4(const f32x4 dv, uint2& hi, uint2& lo) {
  const unsigned b0 = fbits(dv[0]), b1 = fbits(dv[1]), b2 = fbits(dv[2]), b3 = fbits(dv[3]);
  hi.x = __builtin_amdgcn_perm(b1, b0, 0x07060302u);
  hi.y = __builtin_amdgcn_perm(b3, b2, 0x07060302u);
  const float r0 = dv[0] - bitsf(b0 & 0xFFFF0000u);
  const float r1 = dv[1] - bitsf(b1 & 0xFFFF0000u);
  const float r2 = dv[2] - bitsf(b2 & 0xFFFF0000u);
  const float r3 = dv[3] - bitsf(b3 & 0xFFFF0000u);
  lo.x = __builtin_amdgcn_perm(fbits(r1), fbits(r0), 0x07060302u);
  lo.y = __builtin_amdgcn_perm(fbits(r3), fbits(r2), 0x07060302u);
}

__device__ __forceinline__ void split8t(const float* src, bf16x8& hi, bf16x8& lo) {
  #pragma unroll
  for (int j = 0; j < 8; ++j) {
    const unsigned b = fbits(src[j]);
    hi[j] = (short)(b >> 16);
    const float r = src[j] - bitsf(b & 0xFFFF0000u);
    lo[j] = (short)(fbits(r) >> 16);
  }
}

// Barrier WITHOUT the vmcnt(0) drain __syncthreads() emits: LDS producers are
// ordered by lgkmcnt(0); outstanding global ops (out-store, Ht prefetch) carry
// no cross-wave dependency, so draining them at every barrier only stalls.
__device__ __forceinline__ void barrier_lds() {
  asm volatile("s_waitcnt lgkmcnt(0)\n\ts_barrier" ::: "memory");
}

// 8 waves: 0-3 MFMA (2x2 quadrants), 4-7 scalar (16 rows each). 2 barriers/step:
//  seg1: MFMA: M1 = P@F^T (24 mfma); w-partials from f32 acc; M1T store
//        scalar: v=Ph, h.v & h.mu partials, Fmu = F@mu, prefetch h,y
//  seg2: MFMA: acc2 = Q - w w^T/S + F@M1 (24 mfma); P' store
//        scalar: S, kg; out = mu+kg v; mu' = Fmu + kg w; h-buffer
__global__ __launch_bounds__(512, 1) void kalman_ws2(
    const float* __restrict__ emis,   // [N]
    const float* __restrict__ Ht,     // [N,D]
    const float* __restrict__ Fg,     // [D,D]
    const float* __restrict__ Qg,     // [D,D]
    const float* __restrict__ Rg,     // [1]
    const float* __restrict__ mu0,    // [D]
    const float* __restrict__ Sigma0, // [D,D]
    float* __restrict__ out,          // [N,D]
    int n)
{
  __shared__ __align__(16) unsigned short PLhi[D * SB], PLlo[D * SB];   // P (sym, transposed store)
  __shared__ __align__(16) unsigned short M1Thi[D * SB], M1Tlo[D * SB]; // M1^T = F P
  __shared__ __align__(16) float FL[D * SF];    // F row-major f32
  __shared__ __align__(16) float hb_l[2][D];    // H row, double-buffered
  __shared__ __align__(16) float mu_l[2][D];    // predicted mean, double-buffered
  __shared__ __align__(16) float vv_l[D];       // v = P h
  __shared__ __align__(16) float Fmu_l[D];      // F @ mu
  __shared__ __align__(16) float wq_l[2][D];    // w row-half partials (w = M1^T h)
  __shared__ __align__(16) float sred_l[4];     // per-scalar-wave partials of h.v
  __shared__ __align__(16) float sred2_l[4];    // per-scalar-wave partials of h.mu

  const int tid = threadIdx.x;
  const int l   = tid & 63;        // lane
  const int lg  = l >> 4;          // lane group (k-octet)
  const int lm  = l & 15;          // m/n within 16-tile
  const int wv  = tid >> 6;        // wave 0..7
  const int sq  = wv & 3;          // quadrant / scalar-wave index
  const int R0  = (sq >> 1) * 32;  // quadrant row base
  const int C0  = (sq & 1) * 32;   // quadrant col base
  const int W0  = sq * 16;         // scalar wave row base
  const int srow = W0 + (l >> 2);  // scalar matvec row
  const int q   = l & 3;           // scalar column-quarter
  const int c0  = q * 16;

  // ---------------- init ----------------
  for (int i = tid; i < D * D; i += 512) {
    const int rr = i >> 6, cc = i & 63;
    const float s = Sigma0[i];
    const unsigned b = fbits(s);
    PLhi[rr * SB + cc] = (unsigned short)(b >> 16);
    PLlo[rr * SB + cc] = (unsigned short)(fbits(s - bitsf(b & 0xFFFF0000u)) >> 16);
    FL[rr * SF + cc] = Fg[i];
  }
  if (tid < D) { mu_l[0][tid] = mu0[tid]; hb_l[0][tid] = Ht[tid]; }

  // F fragments in registers, kappa(lg,j)=8lg+j consistent for A and B (r3/r5-verified):
  bf16x8 FBhi[2][2], FBlo[2][2], FAhi[2][2], FAlo[2][2];
  #pragma unroll
  for (int nt = 0; nt < 2; ++nt)
    #pragma unroll
    for (int kt = 0; kt < 2; ++kt) {
      split8t(&Fg[(C0 + 16 * nt + lm) * 64 + 8 * lg + 32 * kt], FBhi[nt][kt], FBlo[nt][kt]);
      split8t(&Fg[(R0 + 16 * nt + lm) * 64 + 8 * lg + 32 * kt], FAhi[nt][kt], FAlo[nt][kt]);
    }
  f32x4 Qc[2][2];
  #pragma unroll
  for (int mt = 0; mt < 2; ++mt)
    #pragma unroll
    for (int nt = 0; nt < 2; ++nt)
      #pragma unroll
      for (int j = 0; j < 4; ++j)
        Qc[mt][nt][j] = Qg[(R0 + 16 * mt + 4 * lg + j) * 64 + (C0 + 16 * nt + lm)];

  const float rp = Rg[0] + JITTER;
  __syncthreads();

  float y = 0.f, hn = 0.f;

  #pragma unroll 1
  for (int t = 0; t < n; ++t) {
    const int p = t & 1;

    // ======================= SEGMENT 1 =======================
    if (wv < 4) {
      // h rows for the w-partial (broadcast reads: address uniform per lg-group)
      const f32x4 hr0 = *(const f32x4*)&hb_l[p][R0 + 4 * lg];        // mt=0 rows
      const f32x4 hr1 = *(const f32x4*)&hb_l[p][R0 + 16 + 4 * lg];   // mt=1 rows
      // ---- M1 = P @ F^T ----
      bf16x8 Ahi[2][2], Alo[2][2];
      #pragma unroll
      for (int mt = 0; mt < 2; ++mt)
        #pragma unroll
        for (int kt = 0; kt < 2; ++kt) {
          const int off = (R0 + 16 * mt + lm) * SB + 8 * lg + 32 * kt;
          Ahi[mt][kt] = *(const bf16x8*)&PLhi[off];
          Alo[mt][kt] = *(const bf16x8*)&PLlo[off];
        }
      f32x4 acc1[2][2];
      #pragma unroll
      for (int mt = 0; mt < 2; ++mt)
        #pragma unroll
        for (int nt = 0; nt < 2; ++nt)
          acc1[mt][nt] = (f32x4){0.f, 0.f, 0.f, 0.f};
      __builtin_amdgcn_s_setprio(1);
      #pragma unroll
      for (int kt = 0; kt < 2; ++kt)
        #pragma unroll
        for (int mt = 0; mt < 2; ++mt)
          #pragma unroll
          for (int nt = 0; nt < 2; ++nt) {
            acc1[mt][nt] = __builtin_amdgcn_mfma_f32_16x16x32_bf16(Ahi[mt][kt], FBhi[nt][kt], acc1[mt][nt], 0, 0, 0);
            acc1[mt][nt] = __builtin_amdgcn_mfma_f32_16x16x32_bf16(Ahi[mt][kt], FBlo[nt][kt], acc1[mt][nt], 0, 0, 0);
            acc1[mt][nt] = __builtin_amdgcn_mfma_f32_16x16x32_bf16(Alo[mt][kt], FBhi[nt][kt], acc1[mt][nt], 0, 0, 0);
          }
      __builtin_amdgcn_s_setprio(0);
      // ---- w-partials over this quadrant's rows: pw[nt] = sum_r M1[r][col] h[r] ----
      float pw0 = 0.f, pw1 = 0.f;
      #pragma unroll
      for (int j = 0; j < 4; ++j) {
        pw0 += acc1[0][0][j] * hr0[j] + acc1[1][0][j] * hr1[j];
        pw1 += acc1[0][1][j] * hr0[j] + acc1[1][1][j] * hr1[j];
      }
      pw0 += __shfl_xor(pw0, 16); pw0 += __shfl_xor(pw0, 32);
      pw1 += __shfl_xor(pw1, 16); pw1 += __shfl_xor(pw1, 32);
      if (l < 16) {
        wq_l[R0 >> 5][C0 + lm]      = pw0;
        wq_l[R0 >> 5][C0 + 16 + lm] = pw1;
      }
      // ---- convert + store M1^T ----
      #pragma unroll
      for (int mt = 0; mt < 2; ++mt)
        #pragma unroll
        for (int nt = 0; nt < 2; ++nt) {
          const int idx = (C0 + 16 * nt + lm) * SB + R0 + 16 * mt + 4 * lg;
          uint2 h2, l2;
          split4(acc1[mt][nt], h2, l2);
          *reinterpret_cast<uint2*>(&M1Thi[idx]) = h2;
          *reinterpret_cast<uint2*>(&M1Tlo[idx]) = l2;
        }
    } else {
      // ---- scalar: v = P h, reductions, Fmu = F@mu, prefetch ----
      y = emis[t];
      if (sq == 1 && t + 1 < n) hn = Ht[(size_t)(t + 1) * D + l];
      const f32x4 hq0 = *(const f32x4*)&hb_l[p][c0 + 0];
      const f32x4 hq1 = *(const f32x4*)&hb_l[p][c0 + 4];
      const f32x4 hq2 = *(const f32x4*)&hb_l[p][c0 + 8];
      const f32x4 hq3 = *(const f32x4*)&hb_l[p][c0 + 12];
      const bf16x8 ph0 = *(const bf16x8*)&PLhi[srow * SB + c0];
      const bf16x8 ph1 = *(const bf16x8*)&PLhi[srow * SB + c0 + 8];
      const bf16x8 pl0 = *(const bf16x8*)&PLlo[srow * SB + c0];
      const bf16x8 pl1 = *(const bf16x8*)&PLlo[srow * SB + c0 + 8];
      float pv = 0.f;
      #pragma unroll
      for (int j = 0; j < 4; ++j) {
        pv += (bf2f(ph0[j])     + bf2f(pl0[j]))     * hq0[j];
        pv += (bf2f(ph0[j + 4]) + bf2f(pl0[j + 4])) * hq1[j];
        pv += (bf2f(ph1[j])     + bf2f(pl1[j]))     * hq2[j];
        pv += (bf2f(ph1[j + 4]) + bf2f(pl1[j + 4])) * hq3[j];
      }
      const float hr = hb_l[p][srow];
      float pvs = pv;
      pvs += __shfl_xor(pvs, 1);
      pvs += __shfl_xor(pvs, 2);
      if (q == 0) vv_l[srow] = pvs;
      float sp = hr * pv;   // lane-sum == partial h.v over rows W0..W0+15
      #pragma unroll
      for (int o = 32; o > 0; o >>= 1) sp += __shfl_xor(sp, o);
      if (l == 0) sred_l[sq] = sp;
      float hm = (l < 16) ? hb_l[p][W0 + (l & 15)] * mu_l[p][W0 + (l & 15)] : 0.f;
      #pragma unroll
      for (int o = 8; o > 0; o >>= 1) hm += __shfl_xor(hm, o);
      if (l == 0) sred2_l[sq] = hm;
      // Fmu matvec (mu known at step start)
      float pm = 0.f;
      #pragma unroll
      for (int i2 = 0; i2 < 4; ++i2) {
        const f32x4 fl = *(const f32x4*)&FL[srow * SF + c0 + 4 * i2];
        const f32x4 mc = *(const f32x4*)&mu_l[p][c0 + 4 * i2];
        #pragma unroll
        for (int j = 0; j < 4; ++j) pm += fl[j] * mc[j];
      }
      pm += __shfl_xor(pm, 1);
      pm += __shfl_xor(pm, 2);
      if (q == 0) Fmu_l[srow] = pm;
    }
    barrier_lds();   // B1: M1T, wq, vv, Fmu, sred, sred2 visible

    // ======================= SEGMENT 2 =======================
    if (wv < 4) {
      const f32x4 sr4 = *(const f32x4*)&sred_l[0];
      const float S = rp + sr4[0] + sr4[1] + sr4[2] + sr4[3];
      const float invS = 1.0f / S;
      // assemble w pieces this wave needs
      f32x4 wr[2];
      #pragma unroll
      for (int mt = 0; mt < 2; ++mt) {
        const f32x4 a = *(const f32x4*)&wq_l[0][R0 + 16 * mt + 4 * lg];
        const f32x4 b = *(const f32x4*)&wq_l[1][R0 + 16 * mt + 4 * lg];
        #pragma unroll
        for (int j = 0; j < 4; ++j) wr[mt][j] = a[j] + b[j];
      }
      float wc[2];
      #pragma unroll
      for (int nt = 0; nt < 2; ++nt)
        wc[nt] = (wq_l[0][C0 + 16 * nt + lm] + wq_l[1][C0 + 16 * nt + lm]) * invS;
      // acc2 = Q - w w^T/S, then += F @ M1
      f32x4 acc2[2][2];
      #pragma unroll
      for (int mt = 0; mt < 2; ++mt)
        #pragma unroll
        for (int nt = 0; nt < 2; ++nt)
          #pragma unroll
          for (int j = 0; j < 4; ++j)
            acc2[mt][nt][j] = Qc[mt][nt][j] - wr[mt][j] * wc[nt];
      #pragma unroll
      for (int kt = 0; kt < 2; ++kt) {
        bf16x8 Bhi[2], Blo[2];
        #pragma unroll
        for (int nt = 0; nt < 2; ++nt) {
          const int off = (C0 + 16 * nt + lm) * SB + 8 * lg + 32 * kt;
          Bhi[nt] = *(const bf16x8*)&M1Thi[off];
          Blo[nt] = *(const bf16x8*)&M1Tlo[off];
        }
        __builtin_amdgcn_s_setprio(1);
        #pragma unroll
        for (int mt = 0; mt < 2; ++mt)
          #pragma unroll
          for (int nt = 0; nt < 2; ++nt) {
            acc2[mt][nt] = __builtin_amdgcn_mfma_f32_16x16x32_bf16(FAhi[mt][kt], Bhi[nt], acc2[mt][nt], 0, 0, 0);
            acc2[mt][nt] = __builtin_amdgcn_mfma_f32_16x16x32_bf16(FAhi[mt][kt], Blo[nt], acc2[mt][nt], 0, 0, 0);
            acc2[mt][nt] = __builtin_amdgcn_mfma_f32_16x16x32_bf16(FAlo[mt][kt], Bhi[nt], acc2[mt][nt], 0, 0, 0);
          }
        __builtin_amdgcn_s_setprio(0);
      }
      // store P' transposed (== P', symmetric)
      #pragma unroll
      for (int mt = 0; mt < 2; ++mt)
        #pragma unroll
        for (int nt = 0; nt < 2; ++nt) {
          const int idx = (C0 + 16 * nt + lm) * SB + R0 + 16 * mt + 4 * lg;
          uint2 h2, l2;
          split4(acc2[mt][nt], h2, l2);
          *reinterpret_cast<uint2*>(&PLhi[idx]) = h2;
          *reinterpret_cast<uint2*>(&PLlo[idx]) = l2;
        }
    } else {
      // ---- scalar: S, kg; out; mu' = Fmu + kg w; h-buffer ----
      const float S = rp + sred_l[0] + sred_l[1] + sred_l[2] + sred_l[3];
      const float invS = 1.0f / S;
      const float hmu = sred2_l[0] + sred2_l[1] + sred2_l[2] + sred2_l[3];
      const float kg = (y - hmu) * invS;
      if (sq == 0) out[(size_t)t * D + l] = mu_l[p][l] + kg * vv_l[l];
      if (sq == 2) mu_l[p ^ 1][l] = Fmu_l[l] + kg * (wq_l[0][l] + wq_l[1][l]);
      if (sq == 1 && t + 1 < n) hb_l[p ^ 1][l] = hn;
    }
    barrier_lds();   // B2: P', mu', h ready for next step
  }
}

extern "C" void kernel_launch(void* const* d_in, const int* in_sizes, int n_in,
                              void* d_out, int out_size, void* d_ws, size_t ws_size,
                              hipStream_t stream) {
  (void)n_in; (void)d_ws; (void)ws_size; (void)out_size;
  const float* emis   = (const float*)d_in[0];
  const float* Ht     = (const float*)d_in[1];
  const float* F      = (const float*)d_in[2];
  const float* Q      = (const float*)d_in[3];
  const float* R      = (const float*)d_in[4];
  const float* mu0    = (const float*)d_in[5];
  const float* Sigma0 = (const float*)d_in[6];
  float* out = (float*)d_out;
  const int n = in_sizes[0];
  hipLaunchKernelGGL(kalman_ws2, dim3(1), dim3(512), 0, stream,
                     emis, Ht, F, Q, R, mu0, Sigma0, out, n);
}